// Round 1
// baseline (128.840 us; speedup 1.0000x reference)
//
#include <hip/hip_runtime.h>
#include <math.h>

// SpeciesDetector: pairwise Gaussian-transport KL + sigmoid species gate.
// N=64 agents, M=8 templates, G=64 grid, D=4 state dim.
// Mapping: 1 thread per (n,g,h) = 262144 threads, inner loop over m (8).
//   - a-side (mu_a, sigma_a, omega_a, chi) loaded ONCE per thread (float4).
//   - b-side (4.7 MB total) reused 64x across n -> served by L2/L3.
//   - all 4x4 inverses via adjugate (det is a byproduct -> free slogdet).

namespace {

constexpr int kN = 64;
constexpr int kM = 8;
constexpr int kG = 64;
constexpr int kGH = kG * kG;        // 4096
constexpr float kInvTau = 1.0f / 5.0f;

// Load a 4x4 fp32 matrix (row-major, 16 consecutive floats) via 4 float4s.
__device__ __forceinline__ void load16(const float* __restrict__ p, int idx,
                                       float* __restrict__ o) {
    const float4* p4 = reinterpret_cast<const float4*>(p);
#pragma unroll
    for (int k = 0; k < 4; ++k) {
        float4 v = p4[idx * 4 + k];
        o[4 * k + 0] = v.x;
        o[4 * k + 1] = v.y;
        o[4 * k + 2] = v.z;
        o[4 * k + 3] = v.w;
    }
}

// det of row-major 4x4 via 2x2 minors.
__device__ __forceinline__ float det4(const float* __restrict__ m) {
    float s0 = m[0] * m[5] - m[1] * m[4];
    float s1 = m[0] * m[6] - m[2] * m[4];
    float s2 = m[0] * m[7] - m[3] * m[4];
    float s3 = m[1] * m[6] - m[2] * m[5];
    float s4 = m[1] * m[7] - m[3] * m[5];
    float s5 = m[2] * m[7] - m[3] * m[6];
    float c5 = m[10] * m[15] - m[11] * m[14];
    float c4 = m[9] * m[15] - m[11] * m[13];
    float c3 = m[9] * m[14] - m[10] * m[13];
    float c2 = m[8] * m[15] - m[11] * m[12];
    float c1 = m[8] * m[14] - m[10] * m[12];
    float c0 = m[8] * m[13] - m[9] * m[12];
    return s0 * c5 - s1 * c4 + s2 * c3 + s3 * c2 - s4 * c1 + s5 * c0;
}

// Inverse of row-major 4x4 via adjugate; returns det.
__device__ __forceinline__ float inv4(const float* __restrict__ m,
                                      float* __restrict__ inv) {
    float s0 = m[0] * m[5] - m[1] * m[4];
    float s1 = m[0] * m[6] - m[2] * m[4];
    float s2 = m[0] * m[7] - m[3] * m[4];
    float s3 = m[1] * m[6] - m[2] * m[5];
    float s4 = m[1] * m[7] - m[3] * m[5];
    float s5 = m[2] * m[7] - m[3] * m[6];
    float c5 = m[10] * m[15] - m[11] * m[14];
    float c4 = m[9] * m[15] - m[11] * m[13];
    float c3 = m[9] * m[14] - m[10] * m[13];
    float c2 = m[8] * m[15] - m[11] * m[12];
    float c1 = m[8] * m[14] - m[10] * m[12];
    float c0 = m[8] * m[13] - m[9] * m[12];
    float det = s0 * c5 - s1 * c4 + s2 * c3 + s3 * c2 - s4 * c1 + s5 * c0;
    float r = 1.0f / det;
    inv[0]  = ( m[5]  * c5 - m[6]  * c4 + m[7]  * c3) * r;
    inv[1]  = (-m[1]  * c5 + m[2]  * c4 - m[3]  * c3) * r;
    inv[2]  = ( m[13] * s5 - m[14] * s4 + m[15] * s3) * r;
    inv[3]  = (-m[9]  * s5 + m[10] * s4 - m[11] * s3) * r;
    inv[4]  = (-m[4]  * c5 + m[6]  * c2 - m[7]  * c1) * r;
    inv[5]  = ( m[0]  * c5 - m[2]  * c2 + m[3]  * c1) * r;
    inv[6]  = (-m[12] * s5 + m[14] * s2 - m[15] * s1) * r;
    inv[7]  = ( m[8]  * s5 - m[10] * s2 + m[11] * s1) * r;
    inv[8]  = ( m[4]  * c4 - m[5]  * c2 + m[7]  * c0) * r;
    inv[9]  = (-m[0]  * c4 + m[1]  * c2 - m[3]  * c0) * r;
    inv[10] = ( m[12] * s4 - m[13] * s2 + m[15] * s0) * r;
    inv[11] = (-m[8]  * s4 + m[9]  * s2 - m[11] * s0) * r;
    inv[12] = (-m[4]  * c3 + m[5]  * c1 - m[6]  * c0) * r;
    inv[13] = ( m[0]  * c3 - m[1]  * c1 + m[2]  * c0) * r;
    inv[14] = (-m[12] * s3 + m[13] * s1 - m[14] * s0) * r;
    inv[15] = ( m[8]  * s3 - m[9]  * s1 + m[10] * s0) * r;
    return det;
}

__global__ __launch_bounds__(256) void species_kernel(
    const float* __restrict__ mu_a,    // (N,G,G,D)
    const float* __restrict__ sigma_a, // (N,G,G,D,D)
    const float* __restrict__ omega_a, // (N,G,G,D,D)
    const float* __restrict__ mu_b,    // (M,G,G,D)
    const float* __restrict__ sigma_b, // (M,G,G,D,D)
    const float* __restrict__ omega_b, // (M,G,G,D,D)
    const float* __restrict__ chi,     // (N,G,G)
    float* __restrict__ out)           // (N,M,G,G)
{
    const int t = blockIdx.x * blockDim.x + threadIdx.x;  // n*4096 + g*64 + h
    const int gh = t & (kGH - 1);
    const int n = t >> 12;

    // ---- a-side, loaded once ----
    float Sa[16], Oa[16];
    load16(sigma_a, t, Sa);
    load16(omega_a, t, Oa);
    const float4 ma4 = reinterpret_cast<const float4*>(mu_a)[t];
    const float ma[4] = {ma4.x, ma4.y, ma4.z, ma4.w};
    const float x = chi[t];
    const float ld_a = __logf(fabsf(det4(Sa)));

#pragma unroll 2
    for (int m = 0; m < kM; ++m) {
        const int bb = m * kGH + gh;
        float Ob[16], Sb[16];
        load16(omega_b, bb, Ob);
        load16(sigma_b, bb, Sb);
        const float4 mb4 = reinterpret_cast<const float4*>(mu_b)[bb];
        const float mb[4] = {mb4.x, mb4.y, mb4.z, mb4.w};

        // transport T = Omega_a @ Omega_b^{-1}
        float ObI[16];
        inv4(Ob, ObI);
        float T[16];
#pragma unroll
        for (int i = 0; i < 4; ++i)
#pragma unroll
            for (int k = 0; k < 4; ++k)
                T[i * 4 + k] = Oa[i * 4 + 0] * ObI[0 * 4 + k]
                             + Oa[i * 4 + 1] * ObI[1 * 4 + k]
                             + Oa[i * 4 + 2] * ObI[2 * 4 + k]
                             + Oa[i * 4 + 3] * ObI[3 * 4 + k];

        // mu_b_t = T @ mu_b
        float mbt[4];
#pragma unroll
        for (int i = 0; i < 4; ++i)
            mbt[i] = T[i * 4 + 0] * mb[0] + T[i * 4 + 1] * mb[1]
                   + T[i * 4 + 2] * mb[2] + T[i * 4 + 3] * mb[3];

        // sigma_b_t = T @ Sb @ T^T
        float C[16];
#pragma unroll
        for (int i = 0; i < 4; ++i)
#pragma unroll
            for (int k = 0; k < 4; ++k)
                C[i * 4 + k] = T[i * 4 + 0] * Sb[0 * 4 + k]
                             + T[i * 4 + 1] * Sb[1 * 4 + k]
                             + T[i * 4 + 2] * Sb[2 * 4 + k]
                             + T[i * 4 + 3] * Sb[3 * 4 + k];
        float Bt[16];
#pragma unroll
        for (int i = 0; i < 4; ++i)
#pragma unroll
            for (int l = 0; l < 4; ++l)
                Bt[i * 4 + l] = C[i * 4 + 0] * T[l * 4 + 0]
                              + C[i * 4 + 1] * T[l * 4 + 1]
                              + C[i * 4 + 2] * T[l * 4 + 2]
                              + C[i * 4 + 3] * T[l * 4 + 3];

        // inverse + slogdet of sigma_b_t (det > 0 structurally; fabsf guards)
        float Bi[16];
        const float detb = inv4(Bt, Bi);
        const float ld_b = __logf(fabsf(detb));

        // KL terms
        float diff[4];
#pragma unroll
        for (int i = 0; i < 4; ++i) diff[i] = ma[i] - mbt[i];

        float tr = 0.0f, mah = 0.0f;
#pragma unroll
        for (int i = 0; i < 4; ++i) {
            float w = 0.0f;
#pragma unroll
            for (int j = 0; j < 4; ++j) {
                w += Bi[i * 4 + j] * diff[j];
                tr += Bi[i * 4 + j] * Sa[j * 4 + i];
            }
            mah += diff[i] * w;
        }

        const float kl = 0.5f * (tr + mah - 4.0f + ld_b - ld_a);
        // sigmoid(-kl/tau) * chi ; exp overflow -> inf -> s=0 (correct limit)
        const float s = x / (1.0f + __expf(kl * kInvTau));
        out[(n * kM + m) * kGH + gh] = s;
    }
}

}  // namespace

extern "C" void kernel_launch(void* const* d_in, const int* in_sizes, int n_in,
                              void* d_out, int out_size, void* d_ws, size_t ws_size,
                              hipStream_t stream) {
    const float* mu_a    = (const float*)d_in[0];
    const float* sigma_a = (const float*)d_in[1];
    const float* omega_a = (const float*)d_in[2];
    const float* mu_b    = (const float*)d_in[3];
    const float* sigma_b = (const float*)d_in[4];
    const float* omega_b = (const float*)d_in[5];
    const float* chi     = (const float*)d_in[6];
    float* out = (float*)d_out;

    const int threads = kN * kGH;  // 262144
    species_kernel<<<threads / 256, 256, 0, stream>>>(
        mu_a, sigma_a, omega_a, mu_b, sigma_b, omega_b, chi, out);
}

// Round 2
// 102.448 us; speedup vs baseline: 1.2576x; 1.2576x over previous
//
#include <hip/hip_runtime.h>
#include <math.h>

// SpeciesDetector: pairwise Gaussian-transport KL + sigmoid gate.
// N=64, M=8, G=64, D=4.
//
// R2 restructure: KL terms factor through Omega_a / Omega_b separately:
//   Sigma_bt^-1 = Oa^-T (Ob^T Sb^-1 Ob) Oa^-1 = Oa^-T Q_b Oa^-1
//   mahal = u^T Q_b u,  u = Oa^-1 mu_a - Ob^-1 mu_b
//   tr    = trace(Q_b P_a),  P_a = Oa^-1 Sa Oa^-T   (both symmetric, 10 coeffs)
//   ld_b - ld_a = (ln det Sb - 2 ln|det Ob|) - (ln det Sa - 2 ln|det Oa|)
// -> per-(m,gh) quantities precomputed ONCE into d_ws (2 MB, vs 64x redundant
//    recompute before); main-kernel m-loop is ~45 VALU inst instead of ~550.

namespace {

constexpr int kN = 64;
constexpr int kM = 8;
constexpr int kG = 64;
constexpr int kGH = kG * kG;        // 4096
constexpr int kMB = kM * kGH;       // 32768 b-side entries
constexpr float kInvTau = 1.0f / 5.0f;

__device__ __forceinline__ void load16(const float* __restrict__ p, int idx,
                                       float* __restrict__ o) {
    const float4* p4 = reinterpret_cast<const float4*>(p);
#pragma unroll
    for (int k = 0; k < 4; ++k) {
        float4 v = p4[idx * 4 + k];
        o[4 * k + 0] = v.x;
        o[4 * k + 1] = v.y;
        o[4 * k + 2] = v.z;
        o[4 * k + 3] = v.w;
    }
}

__device__ __forceinline__ float det4(const float* __restrict__ m) {
    float s0 = m[0] * m[5] - m[1] * m[4];
    float s1 = m[0] * m[6] - m[2] * m[4];
    float s2 = m[0] * m[7] - m[3] * m[4];
    float s3 = m[1] * m[6] - m[2] * m[5];
    float s4 = m[1] * m[7] - m[3] * m[5];
    float s5 = m[2] * m[7] - m[3] * m[6];
    float c5 = m[10] * m[15] - m[11] * m[14];
    float c4 = m[9] * m[15] - m[11] * m[13];
    float c3 = m[9] * m[14] - m[10] * m[13];
    float c2 = m[8] * m[15] - m[11] * m[12];
    float c1 = m[8] * m[14] - m[10] * m[12];
    float c0 = m[8] * m[13] - m[9] * m[12];
    return s0 * c5 - s1 * c4 + s2 * c3 + s3 * c2 - s4 * c1 + s5 * c0;
}

// Adjugate inverse of row-major 4x4; returns det. rcp is the HW approx
// (~1 ulp) -- fine vs 9.6e-3 threshold on well-conditioned inputs.
__device__ __forceinline__ float inv4(const float* __restrict__ m,
                                      float* __restrict__ inv) {
    float s0 = m[0] * m[5] - m[1] * m[4];
    float s1 = m[0] * m[6] - m[2] * m[4];
    float s2 = m[0] * m[7] - m[3] * m[4];
    float s3 = m[1] * m[6] - m[2] * m[5];
    float s4 = m[1] * m[7] - m[3] * m[5];
    float s5 = m[2] * m[7] - m[3] * m[6];
    float c5 = m[10] * m[15] - m[11] * m[14];
    float c4 = m[9] * m[15] - m[11] * m[13];
    float c3 = m[9] * m[14] - m[10] * m[13];
    float c2 = m[8] * m[15] - m[11] * m[12];
    float c1 = m[8] * m[14] - m[10] * m[12];
    float c0 = m[8] * m[13] - m[9] * m[12];
    float det = s0 * c5 - s1 * c4 + s2 * c3 + s3 * c2 - s4 * c1 + s5 * c0;
    float r = __builtin_amdgcn_rcpf(det);
    inv[0]  = ( m[5]  * c5 - m[6]  * c4 + m[7]  * c3) * r;
    inv[1]  = (-m[1]  * c5 + m[2]  * c4 - m[3]  * c3) * r;
    inv[2]  = ( m[13] * s5 - m[14] * s4 + m[15] * s3) * r;
    inv[3]  = (-m[9]  * s5 + m[10] * s4 - m[11] * s3) * r;
    inv[4]  = (-m[4]  * c5 + m[6]  * c2 - m[7]  * c1) * r;
    inv[5]  = ( m[0]  * c5 - m[2]  * c2 + m[3]  * c1) * r;
    inv[6]  = (-m[12] * s5 + m[14] * s2 - m[15] * s1) * r;
    inv[7]  = ( m[8]  * s5 - m[10] * s2 + m[11] * s1) * r;
    inv[8]  = ( m[4]  * c4 - m[5]  * c2 + m[7]  * c0) * r;
    inv[9]  = (-m[0]  * c4 + m[1]  * c2 - m[3]  * c0) * r;
    inv[10] = ( m[12] * s4 - m[13] * s2 + m[15] * s0) * r;
    inv[11] = (-m[8]  * s4 + m[9]  * s2 - m[11] * s0) * r;
    inv[12] = (-m[4]  * c3 + m[5]  * c1 - m[6]  * c0) * r;
    inv[13] = ( m[0]  * c3 - m[1]  * c1 + m[2]  * c0) * r;
    inv[14] = (-m[12] * s3 + m[13] * s1 - m[14] * s0) * r;
    inv[15] = ( m[8]  * s3 - m[9]  * s1 + m[10] * s0) * r;
    return det;
}

// Per-(m,gh): Q_b = Ob^T Sb^-1 Ob (sym, off-diag pre-doubled), v_b = Ob^-1 mu_b,
// lb = ln det Sb - 2 ln|det Ob|. Packed 16 floats:
//   q0={Q00,2Q01,2Q02,2Q03} q1={Q11,2Q12,2Q13,Q22} q2={2Q23,Q33,lb,0} q3=v_b
__global__ __launch_bounds__(128) void precompute_b_kernel(
    const float* __restrict__ mu_b,
    const float* __restrict__ sigma_b,
    const float* __restrict__ omega_b,
    float4* __restrict__ ws)
{
    const int idx = blockIdx.x * blockDim.x + threadIdx.x;  // m*4096 + gh
    float Sb[16], Ob[16];
    load16(sigma_b, idx, Sb);
    load16(omega_b, idx, Ob);
    float SbI[16], ObI[16];
    const float detSb = inv4(Sb, SbI);
    const float detOb = inv4(Ob, ObI);
    const float4 mb4 = reinterpret_cast<const float4*>(mu_b)[idx];
    const float mb[4] = {mb4.x, mb4.y, mb4.z, mb4.w};

    // R = Sb^-1 * Ob
    float R[16];
#pragma unroll
    for (int i = 0; i < 4; ++i)
#pragma unroll
        for (int k = 0; k < 4; ++k)
            R[i * 4 + k] = SbI[i * 4 + 0] * Ob[0 * 4 + k]
                         + SbI[i * 4 + 1] * Ob[1 * 4 + k]
                         + SbI[i * 4 + 2] * Ob[2 * 4 + k]
                         + SbI[i * 4 + 3] * Ob[3 * 4 + k];
    // Q[i][k] = sum_j Ob[j][i] * R[j][k], upper-tri only, off-diag doubled
    float Qf[10];
    int pi = 0;
#pragma unroll
    for (int i = 0; i < 4; ++i)
#pragma unroll
        for (int k = 0; k < 4; ++k) {
            if (k < i) continue;
            float q = Ob[0 * 4 + i] * R[0 * 4 + k]
                    + Ob[1 * 4 + i] * R[1 * 4 + k]
                    + Ob[2 * 4 + i] * R[2 * 4 + k]
                    + Ob[3 * 4 + i] * R[3 * 4 + k];
            Qf[pi++] = (i == k) ? q : 2.0f * q;
        }
    float v[4];
#pragma unroll
    for (int i = 0; i < 4; ++i)
        v[i] = ObI[i * 4 + 0] * mb[0] + ObI[i * 4 + 1] * mb[1]
             + ObI[i * 4 + 2] * mb[2] + ObI[i * 4 + 3] * mb[3];

    const float lb = __logf(fabsf(detSb)) - 2.0f * __logf(fabsf(detOb));

    float4* o = ws + idx * 4;
    o[0] = make_float4(Qf[0], Qf[1], Qf[2], Qf[3]);
    o[1] = make_float4(Qf[4], Qf[5], Qf[6], Qf[7]);
    o[2] = make_float4(Qf[8], Qf[9], lb, 0.0f);
    o[3] = make_float4(v[0], v[1], v[2], v[3]);
}

__global__ __launch_bounds__(256) void species_kernel(
    const float* __restrict__ mu_a,    // (N,G,G,D)
    const float* __restrict__ sigma_a, // (N,G,G,D,D)
    const float* __restrict__ omega_a, // (N,G,G,D,D)
    const float* __restrict__ chi,     // (N,G,G)
    const float4* __restrict__ ws,     // packed b-side, 32768 * 4 float4
    float* __restrict__ out)           // (N,M,G,G)
{
    const int t = blockIdx.x * blockDim.x + threadIdx.x;  // n*4096 + gh
    const int gh = t & (kGH - 1);
    const int n = t >> 12;

    // ---- per-thread a-side setup (once) ----
    float Sa[16], Oa[16], OaI[16];
    load16(sigma_a, t, Sa);
    load16(omega_a, t, Oa);
    const float detOa = inv4(Oa, OaI);
    const float detSa = det4(Sa);
    const float la = __logf(fabsf(detSa)) - 2.0f * __logf(fabsf(detOa));
    const float4 ma4 = reinterpret_cast<const float4*>(mu_a)[t];
    const float ma[4] = {ma4.x, ma4.y, ma4.z, ma4.w};
    const float x = chi[t];

    // w = Oa^-1 mu_a
    float w[4];
#pragma unroll
    for (int i = 0; i < 4; ++i)
        w[i] = OaI[i * 4 + 0] * ma[0] + OaI[i * 4 + 1] * ma[1]
             + OaI[i * 4 + 2] * ma[2] + OaI[i * 4 + 3] * ma[3];

    // P = Oa^-1 Sa Oa^-T (symmetric, 10 coeffs, plain entries)
    float Mt[16];
#pragma unroll
    for (int i = 0; i < 4; ++i)
#pragma unroll
        for (int k = 0; k < 4; ++k)
            Mt[i * 4 + k] = OaI[i * 4 + 0] * Sa[0 * 4 + k]
                          + OaI[i * 4 + 1] * Sa[1 * 4 + k]
                          + OaI[i * 4 + 2] * Sa[2 * 4 + k]
                          + OaI[i * 4 + 3] * Sa[3 * 4 + k];
    float Pf[10];
    {
        int pi = 0;
#pragma unroll
        for (int i = 0; i < 4; ++i)
#pragma unroll
            for (int k = 0; k < 4; ++k) {
                if (k < i) continue;
                Pf[pi++] = Mt[i * 4 + 0] * OaI[k * 4 + 0]
                         + Mt[i * 4 + 1] * OaI[k * 4 + 1]
                         + Mt[i * 4 + 2] * OaI[k * 4 + 2]
                         + Mt[i * 4 + 3] * OaI[k * 4 + 3];
            }
    }

    // ---- m-loop: 16 loaded floats + two 10-term symmetric dots ----
#pragma unroll
    for (int m = 0; m < kM; ++m) {
        const float4* b = ws + (m * kGH + gh) * 4;
        const float4 q0 = b[0];
        const float4 q1 = b[1];
        const float4 q2 = b[2];
        const float4 q3 = b[3];

        const float u0 = w[0] - q3.x;
        const float u1 = w[1] - q3.y;
        const float u2 = w[2] - q3.z;
        const float u3 = w[3] - q3.w;

        float tr = q0.x * Pf[0] + q0.y * Pf[1] + q0.z * Pf[2] + q0.w * Pf[3]
                 + q1.x * Pf[4] + q1.y * Pf[5] + q1.z * Pf[6] + q1.w * Pf[7]
                 + q2.x * Pf[8] + q2.y * Pf[9];
        float mah = q0.x * (u0 * u0) + q0.y * (u0 * u1) + q0.z * (u0 * u2)
                  + q0.w * (u0 * u3) + q1.x * (u1 * u1) + q1.y * (u1 * u2)
                  + q1.z * (u1 * u3) + q1.w * (u2 * u2) + q2.x * (u2 * u3)
                  + q2.y * (u3 * u3);

        const float kl = 0.5f * (tr + mah - 4.0f + q2.z - la);
        // sigmoid(-kl/tau)*chi; e->inf => rcp(inf)=0 (correct limit)
        const float e = __expf(kl * kInvTau);
        const float s = x * __builtin_amdgcn_rcpf(1.0f + e);
        out[(n * kM + m) * kGH + gh] = s;
    }
}

}  // namespace

extern "C" void kernel_launch(void* const* d_in, const int* in_sizes, int n_in,
                              void* d_out, int out_size, void* d_ws, size_t ws_size,
                              hipStream_t stream) {
    const float* mu_a    = (const float*)d_in[0];
    const float* sigma_a = (const float*)d_in[1];
    const float* omega_a = (const float*)d_in[2];
    const float* mu_b    = (const float*)d_in[3];
    const float* sigma_b = (const float*)d_in[4];
    const float* omega_b = (const float*)d_in[5];
    const float* chi     = (const float*)d_in[6];
    float* out = (float*)d_out;
    float4* ws = (float4*)d_ws;  // needs 32768*64 B = 2 MiB

    precompute_b_kernel<<<kMB / 128, 128, 0, stream>>>(mu_b, sigma_b, omega_b, ws);

    const int threads = kN * kGH;  // 262144
    species_kernel<<<threads / 256, 256, 0, stream>>>(
        mu_a, sigma_a, omega_a, chi, ws, out);
}

// Round 3
// 98.221 us; speedup vs baseline: 1.3117x; 1.0430x over previous
//
#include <hip/hip_runtime.h>
#include <math.h>

// SpeciesDetector: pairwise Gaussian-transport KL + sigmoid gate.
// N=64, M=8, G=64, D=4.
//
// Factored KL (R2):
//   Sigma_bt^-1 = Oa^-T (Ob^T Sb^-1 Ob) Oa^-1 = Oa^-T Q_b Oa^-1
//   mahal = u^T Q_b u,  u = Oa^-1 mu_a - Ob^-1 mu_b
//   tr    = trace(Q_b P_a),  P_a = Oa^-1 Sa Oa^-T   (both symmetric, 10 coeffs)
//   ld_b - ld_a = (ln det Sb - 2 ln|det Ob|) - (ln det Sa - 2 ln|det Oa|)
//
// R3: ws layout transposed to PLANE-MAJOR float4 (4 planes x 32768 entries).
// Entry-major AoS gave lane-stride 64 B -> each wave load touched 64
// discontiguous cache lines (4x L1 line-request amplification). Plane-major
// makes consecutive gh lanes hit consecutive float4s -> one contiguous 1 KB
// transaction per load, same as the a-side streams.

namespace {

constexpr int kN = 64;
constexpr int kM = 8;
constexpr int kG = 64;
constexpr int kGH = kG * kG;        // 4096
constexpr int kMB = kM * kGH;       // 32768 b-side entries
constexpr float kInvTau = 1.0f / 5.0f;

__device__ __forceinline__ void load16(const float* __restrict__ p, int idx,
                                       float* __restrict__ o) {
    const float4* p4 = reinterpret_cast<const float4*>(p);
#pragma unroll
    for (int k = 0; k < 4; ++k) {
        float4 v = p4[idx * 4 + k];
        o[4 * k + 0] = v.x;
        o[4 * k + 1] = v.y;
        o[4 * k + 2] = v.z;
        o[4 * k + 3] = v.w;
    }
}

__device__ __forceinline__ float det4(const float* __restrict__ m) {
    float s0 = m[0] * m[5] - m[1] * m[4];
    float s1 = m[0] * m[6] - m[2] * m[4];
    float s2 = m[0] * m[7] - m[3] * m[4];
    float s3 = m[1] * m[6] - m[2] * m[5];
    float s4 = m[1] * m[7] - m[3] * m[5];
    float s5 = m[2] * m[7] - m[3] * m[6];
    float c5 = m[10] * m[15] - m[11] * m[14];
    float c4 = m[9] * m[15] - m[11] * m[13];
    float c3 = m[9] * m[14] - m[10] * m[13];
    float c2 = m[8] * m[15] - m[11] * m[12];
    float c1 = m[8] * m[14] - m[10] * m[12];
    float c0 = m[8] * m[13] - m[9] * m[12];
    return s0 * c5 - s1 * c4 + s2 * c3 + s3 * c2 - s4 * c1 + s5 * c0;
}

// Adjugate inverse of row-major 4x4; returns det. rcp is HW approx (~1 ulp).
__device__ __forceinline__ float inv4(const float* __restrict__ m,
                                      float* __restrict__ inv) {
    float s0 = m[0] * m[5] - m[1] * m[4];
    float s1 = m[0] * m[6] - m[2] * m[4];
    float s2 = m[0] * m[7] - m[3] * m[4];
    float s3 = m[1] * m[6] - m[2] * m[5];
    float s4 = m[1] * m[7] - m[3] * m[5];
    float s5 = m[2] * m[7] - m[3] * m[6];
    float c5 = m[10] * m[15] - m[11] * m[14];
    float c4 = m[9] * m[15] - m[11] * m[13];
    float c3 = m[9] * m[14] - m[10] * m[13];
    float c2 = m[8] * m[15] - m[11] * m[12];
    float c1 = m[8] * m[14] - m[10] * m[12];
    float c0 = m[8] * m[13] - m[9] * m[12];
    float det = s0 * c5 - s1 * c4 + s2 * c3 + s3 * c2 - s4 * c1 + s5 * c0;
    float r = __builtin_amdgcn_rcpf(det);
    inv[0]  = ( m[5]  * c5 - m[6]  * c4 + m[7]  * c3) * r;
    inv[1]  = (-m[1]  * c5 + m[2]  * c4 - m[3]  * c3) * r;
    inv[2]  = ( m[13] * s5 - m[14] * s4 + m[15] * s3) * r;
    inv[3]  = (-m[9]  * s5 + m[10] * s4 - m[11] * s3) * r;
    inv[4]  = (-m[4]  * c5 + m[6]  * c2 - m[7]  * c1) * r;
    inv[5]  = ( m[0]  * c5 - m[2]  * c2 + m[3]  * c1) * r;
    inv[6]  = (-m[12] * s5 + m[14] * s2 - m[15] * s1) * r;
    inv[7]  = ( m[8]  * s5 - m[10] * s2 + m[11] * s1) * r;
    inv[8]  = ( m[4]  * c4 - m[5]  * c2 + m[7]  * c0) * r;
    inv[9]  = (-m[0]  * c4 + m[1]  * c2 - m[3]  * c0) * r;
    inv[10] = ( m[12] * s4 - m[13] * s2 + m[15] * s0) * r;
    inv[11] = (-m[8]  * s4 + m[9]  * s2 - m[11] * s0) * r;
    inv[12] = (-m[4]  * c3 + m[5]  * c1 - m[6]  * c0) * r;
    inv[13] = ( m[0]  * c3 - m[1]  * c1 + m[2]  * c0) * r;
    inv[14] = (-m[12] * s3 + m[13] * s1 - m[14] * s0) * r;
    inv[15] = ( m[8]  * s3 - m[9]  * s1 + m[10] * s0) * r;
    return det;
}

// Per-(m,gh): Q_b = Ob^T Sb^-1 Ob (sym, off-diag pre-doubled), v = Ob^-1 mu_b,
// lb = ln det Sb - 2 ln|det Ob|. Plane-major float4:
//   ws4[0*32768+idx] = {Q00,2Q01,2Q02,2Q03}
//   ws4[1*32768+idx] = {Q11,2Q12,2Q13,Q22}
//   ws4[2*32768+idx] = {2Q23,Q33,lb,0}
//   ws4[3*32768+idx] = v
__global__ __launch_bounds__(256) void precompute_b_kernel(
    const float* __restrict__ mu_b,
    const float* __restrict__ sigma_b,
    const float* __restrict__ omega_b,
    float4* __restrict__ ws)
{
    const int idx = blockIdx.x * blockDim.x + threadIdx.x;  // m*4096 + gh
    float Sb[16], Ob[16];
    load16(sigma_b, idx, Sb);
    load16(omega_b, idx, Ob);
    float SbI[16], ObI[16];
    const float detSb = inv4(Sb, SbI);
    const float detOb = inv4(Ob, ObI);
    const float4 mb4 = reinterpret_cast<const float4*>(mu_b)[idx];
    const float mb[4] = {mb4.x, mb4.y, mb4.z, mb4.w};

    // R = Sb^-1 * Ob
    float R[16];
#pragma unroll
    for (int i = 0; i < 4; ++i)
#pragma unroll
        for (int k = 0; k < 4; ++k)
            R[i * 4 + k] = SbI[i * 4 + 0] * Ob[0 * 4 + k]
                         + SbI[i * 4 + 1] * Ob[1 * 4 + k]
                         + SbI[i * 4 + 2] * Ob[2 * 4 + k]
                         + SbI[i * 4 + 3] * Ob[3 * 4 + k];
    // Q[i][k] = sum_j Ob[j][i] * R[j][k], upper-tri, off-diag doubled
    float Qf[10];
    int pi = 0;
#pragma unroll
    for (int i = 0; i < 4; ++i)
#pragma unroll
        for (int k = 0; k < 4; ++k) {
            if (k < i) continue;
            float q = Ob[0 * 4 + i] * R[0 * 4 + k]
                    + Ob[1 * 4 + i] * R[1 * 4 + k]
                    + Ob[2 * 4 + i] * R[2 * 4 + k]
                    + Ob[3 * 4 + i] * R[3 * 4 + k];
            Qf[pi++] = (i == k) ? q : 2.0f * q;
        }
    float v[4];
#pragma unroll
    for (int i = 0; i < 4; ++i)
        v[i] = ObI[i * 4 + 0] * mb[0] + ObI[i * 4 + 1] * mb[1]
             + ObI[i * 4 + 2] * mb[2] + ObI[i * 4 + 3] * mb[3];

    const float lb = __logf(fabsf(detSb)) - 2.0f * __logf(fabsf(detOb));

    // plane-major, coalesced stores
    ws[0 * kMB + idx] = make_float4(Qf[0], Qf[1], Qf[2], Qf[3]);
    ws[1 * kMB + idx] = make_float4(Qf[4], Qf[5], Qf[6], Qf[7]);
    ws[2 * kMB + idx] = make_float4(Qf[8], Qf[9], lb, 0.0f);
    ws[3 * kMB + idx] = make_float4(v[0], v[1], v[2], v[3]);
}

__global__ __launch_bounds__(256) void species_kernel(
    const float* __restrict__ mu_a,    // (N,G,G,D)
    const float* __restrict__ sigma_a, // (N,G,G,D,D)
    const float* __restrict__ omega_a, // (N,G,G,D,D)
    const float* __restrict__ chi,     // (N,G,G)
    const float4* __restrict__ ws,     // plane-major b-side, 4 x 32768 float4
    float* __restrict__ out)           // (N,M,G,G)
{
    const int t = blockIdx.x * blockDim.x + threadIdx.x;  // n*4096 + gh
    const int gh = t & (kGH - 1);
    const int n = t >> 12;

    // ---- per-thread a-side setup (once) ----
    float Sa[16], Oa[16], OaI[16];
    load16(sigma_a, t, Sa);
    load16(omega_a, t, Oa);
    const float detOa = inv4(Oa, OaI);
    const float detSa = det4(Sa);
    const float la = __logf(fabsf(detSa)) - 2.0f * __logf(fabsf(detOa));
    const float4 ma4 = reinterpret_cast<const float4*>(mu_a)[t];
    const float ma[4] = {ma4.x, ma4.y, ma4.z, ma4.w};
    const float x = chi[t];

    // w = Oa^-1 mu_a
    float w[4];
#pragma unroll
    for (int i = 0; i < 4; ++i)
        w[i] = OaI[i * 4 + 0] * ma[0] + OaI[i * 4 + 1] * ma[1]
             + OaI[i * 4 + 2] * ma[2] + OaI[i * 4 + 3] * ma[3];

    // P = Oa^-1 Sa Oa^-T (symmetric, 10 coeffs)
    float Mt[16];
#pragma unroll
    for (int i = 0; i < 4; ++i)
#pragma unroll
        for (int k = 0; k < 4; ++k)
            Mt[i * 4 + k] = OaI[i * 4 + 0] * Sa[0 * 4 + k]
                          + OaI[i * 4 + 1] * Sa[1 * 4 + k]
                          + OaI[i * 4 + 2] * Sa[2 * 4 + k]
                          + OaI[i * 4 + 3] * Sa[3 * 4 + k];
    float Pf[10];
    {
        int pi = 0;
#pragma unroll
        for (int i = 0; i < 4; ++i)
#pragma unroll
            for (int k = 0; k < 4; ++k) {
                if (k < i) continue;
                Pf[pi++] = Mt[i * 4 + 0] * OaI[k * 4 + 0]
                         + Mt[i * 4 + 1] * OaI[k * 4 + 1]
                         + Mt[i * 4 + 2] * OaI[k * 4 + 2]
                         + Mt[i * 4 + 3] * OaI[k * 4 + 3];
            }
    }

    // ---- m-loop: 4 coalesced float4 loads + two 10-term symmetric dots ----
#pragma unroll
    for (int m = 0; m < kM; ++m) {
        const int bb = m * kGH + gh;
        const float4 q0 = ws[0 * kMB + bb];
        const float4 q1 = ws[1 * kMB + bb];
        const float4 q2 = ws[2 * kMB + bb];
        const float4 q3 = ws[3 * kMB + bb];

        const float u0 = w[0] - q3.x;
        const float u1 = w[1] - q3.y;
        const float u2 = w[2] - q3.z;
        const float u3 = w[3] - q3.w;

        float tr = q0.x * Pf[0] + q0.y * Pf[1] + q0.z * Pf[2] + q0.w * Pf[3]
                 + q1.x * Pf[4] + q1.y * Pf[5] + q1.z * Pf[6] + q1.w * Pf[7]
                 + q2.x * Pf[8] + q2.y * Pf[9];
        float mah = q0.x * (u0 * u0) + q0.y * (u0 * u1) + q0.z * (u0 * u2)
                  + q0.w * (u0 * u3) + q1.x * (u1 * u1) + q1.y * (u1 * u2)
                  + q1.z * (u1 * u3) + q1.w * (u2 * u2) + q2.x * (u2 * u3)
                  + q2.y * (u3 * u3);

        const float kl = 0.5f * (tr + mah - 4.0f + q2.z - la);
        // sigmoid(-kl/tau)*chi; e->inf => rcp(inf)=0 (correct limit)
        const float e = __expf(kl * kInvTau);
        const float s = x * __builtin_amdgcn_rcpf(1.0f + e);
        out[(n * kM + m) * kGH + gh] = s;
    }
}

}  // namespace

extern "C" void kernel_launch(void* const* d_in, const int* in_sizes, int n_in,
                              void* d_out, int out_size, void* d_ws, size_t ws_size,
                              hipStream_t stream) {
    const float* mu_a    = (const float*)d_in[0];
    const float* sigma_a = (const float*)d_in[1];
    const float* omega_a = (const float*)d_in[2];
    const float* mu_b    = (const float*)d_in[3];
    const float* sigma_b = (const float*)d_in[4];
    const float* omega_b = (const float*)d_in[5];
    const float* chi     = (const float*)d_in[6];
    float* out = (float*)d_out;
    float4* ws = (float4*)d_ws;  // needs 4*32768*16 B = 2 MiB

    precompute_b_kernel<<<kMB / 256, 256, 0, stream>>>(mu_b, sigma_b, omega_b, ws);

    const int threads = kN * kGH;  // 262144
    species_kernel<<<threads / 256, 256, 0, stream>>>(
        mu_a, sigma_a, omega_a, chi, ws, out);
}